// Round 5
// baseline (510.673 us; speedup 1.0000x reference)
//
#include <hip/hip_runtime.h>
#include <math.h>

// mHC fused kernel: per block = 8 tokens.
// Phase 1: H[tok][24] = W_phi . hs_flat  (+ normsq), waves split outputs 6-way
// Phase 2: sigmoid gates + 4x4 sinkhorn (20 iters) via in-wave shuffles
// Phase 3: output recombination, float4 loads/stores (hs re-read hits L2)

__global__ __launch_bounds__(256)
void mhc_fused(const float* __restrict__ hs,
               const float* __restrict__ Wphi,
               const float* __restrict__ av,
               const float* __restrict__ bv,
               float* __restrict__ out)
{
    const int tid  = threadIdx.x;
    const int wave = tid >> 6;
    const int lane = tid & 63;
    const long long t0 = (long long)blockIdx.x * 8;

    __shared__ float Hlds[8][25];
    __shared__ float preL[8][4];
    __shared__ float postL[8][4];
    __shared__ float resL[8][16];

    // ---------------- Phase 1: matvec + normsq ----------------
    const int obase = wave * 6;
    const float4* hs4 = reinterpret_cast<const float4*>(hs + t0 * 8192);
    const float4* W4  = reinterpret_cast<const float4*>(Wphi) + (size_t)obase * 2048;

    float acc[8][6];
    float accN[8];
#pragma unroll
    for (int t = 0; t < 8; ++t) {
        accN[t] = 0.f;
#pragma unroll
        for (int o = 0; o < 6; ++o) acc[t][o] = 0.f;
    }

    for (int i = 0; i < 32; ++i) {
        const int k4 = lane + (i << 6);   // float4 index within the 2048-wide row
        float4 h[8];
#pragma unroll
        for (int t = 0; t < 8; ++t) h[t] = hs4[t * 2048 + k4];
#pragma unroll
        for (int o = 0; o < 6; ++o) {
            const float4 w = W4[o * 2048 + k4];
#pragma unroll
            for (int t = 0; t < 8; ++t)
                acc[t][o] += w.x * h[t].x + w.y * h[t].y + w.z * h[t].z + w.w * h[t].w;
        }
        if (wave == 0) {
#pragma unroll
            for (int t = 0; t < 8; ++t)
                accN[t] += h[t].x * h[t].x + h[t].y * h[t].y
                         + h[t].z * h[t].z + h[t].w * h[t].w;
        }
    }

    // butterfly reduce across 64 lanes, lane 0 writes LDS
#pragma unroll
    for (int t = 0; t < 8; ++t) {
#pragma unroll
        for (int o = 0; o < 6; ++o) {
            float v = acc[t][o];
            v += __shfl_xor(v, 32); v += __shfl_xor(v, 16); v += __shfl_xor(v, 8);
            v += __shfl_xor(v, 4);  v += __shfl_xor(v, 2);  v += __shfl_xor(v, 1);
            if (lane == 0) Hlds[t][obase + o] = v;
        }
    }
    if (wave == 0) {
#pragma unroll
        for (int t = 0; t < 8; ++t) {
            float v = accN[t];
            v += __shfl_xor(v, 32); v += __shfl_xor(v, 16); v += __shfl_xor(v, 8);
            v += __shfl_xor(v, 4);  v += __shfl_xor(v, 2);  v += __shfl_xor(v, 1);
            if (lane == 0) Hlds[t][24] = v;
        }
    }
    __syncthreads();

    // ---------------- Phase 2: gates + sinkhorn ----------------
    // threads 0..127: token t = tid>>4, entry e = tid&15 (e = m*4 + n)
    if (tid < 128) {
        const int t = tid >> 4;
        const int e = tid & 15;
        const float normsq = Hlds[t][24];
        const float inv_r  = sqrtf(8192.0f / normsq);
        const float a0 = av[0], a1 = av[1], a2 = av[2];

        float K = expf(inv_r * Hlds[t][8 + e] * a2 + bv[8 + e]);
        for (int it = 0; it < 20; ++it) {
            // row-normalize (sum over n: xor low 2 bits)
            float rs = K + __shfl_xor(K, 1);
            rs += __shfl_xor(rs, 2);
            K = K / (rs + 1e-20f);
            // col-normalize (sum over m: xor bits 2,3)
            float cs = K + __shfl_xor(K, 4);
            cs += __shfl_xor(cs, 8);
            K = K / (cs + 1e-20f);
        }
        resL[t][e] = K;

        if (e < 4) {
            float xp = inv_r * Hlds[t][e] * a0 + bv[e];
            preL[t][e] = 1.0f / (1.0f + expf(-xp));
            float xq = inv_r * Hlds[t][4 + e] * a1 + bv[4 + e];
            postL[t][e] = 2.0f / (1.0f + expf(-xq));
        }
    }
    __syncthreads();

    // ---------------- Phase 3: outputs ----------------
    const float4* hsr  = reinterpret_cast<const float4*>(hs + t0 * 8192);
    float4*       out4 = reinterpret_cast<float4*>(out) + t0 * 2048;

    for (int t = 0; t < 8; ++t) {
        float pre[4], post[4], res[16];
#pragma unroll
        for (int n = 0; n < 4; ++n) { pre[n] = preL[t][n]; post[n] = postL[t][n]; }
#pragma unroll
        for (int e = 0; e < 16; ++e) res[e] = resL[t][e];

#pragma unroll
        for (int ii = 0; ii < 2; ++ii) {
            const int c4 = tid + (ii << 8);   // 0..511 float4 col within a branch row
            float4 h[4];
#pragma unroll
            for (int n = 0; n < 4; ++n) h[n] = hsr[t * 2048 + n * 512 + c4];

            float4 hp;
            hp.x = pre[0]*h[0].x + pre[1]*h[1].x + pre[2]*h[2].x + pre[3]*h[3].x;
            hp.y = pre[0]*h[0].y + pre[1]*h[1].y + pre[2]*h[2].y + pre[3]*h[3].y;
            hp.z = pre[0]*h[0].z + pre[1]*h[1].z + pre[2]*h[2].z + pre[3]*h[3].z;
            hp.w = pre[0]*h[0].w + pre[1]*h[1].w + pre[2]*h[2].w + pre[3]*h[3].w;

#pragma unroll
            for (int m = 0; m < 4; ++m) {
                const float r0 = res[m*4+0], r1 = res[m*4+1], r2 = res[m*4+2], r3 = res[m*4+3];
                const float pm = post[m];
                float4 o;
                o.x = pm*hp.x + r0*h[0].x + r1*h[1].x + r2*h[2].x + r3*h[3].x;
                o.y = pm*hp.y + r0*h[0].y + r1*h[1].y + r2*h[2].y + r3*h[3].y;
                o.z = pm*hp.z + r0*h[0].z + r1*h[1].z + r2*h[2].z + r3*h[3].z;
                o.w = pm*hp.w + r0*h[0].w + r1*h[1].w + r2*h[2].w + r3*h[3].w;
                out4[t * 2048 + m * 512 + c4] = o;
            }
        }
    }
}

extern "C" void kernel_launch(void* const* d_in, const int* in_sizes, int n_in,
                              void* d_out, int out_size, void* d_ws, size_t ws_size,
                              hipStream_t stream) {
    const float* hs  = (const float*)d_in[0];   // [B, L, 4, 2048] fp32
    const float* Wp  = (const float*)d_in[1];   // [24, 8192] fp32
    const float* av  = (const float*)d_in[2];   // [3]
    const float* bv  = (const float*)d_in[3];   // [24]
    float* out = (float*)d_out;                 // [B, L, 4, 2048] fp32

    const int tokens = in_sizes[0] / 8192;      // 8192
    const int blocks = tokens / 8;              // 1024

    mhc_fused<<<blocks, 256, 0, stream>>>(hs, Wp, av, bv, out);
}